// Round 10
// baseline (214.761 us; speedup 1.0000x reference)
//
#include <hip/hip_runtime.h>
#include <stdint.h>
#include <math.h>

#define SLEN 2048
#define EPT 32               // elements per lane: one wave owns a full row
#define NTHREADS 256         // 4 waves = 4 independent rows per block
#define ROWS_PER_BLOCK 4
#define NCHUNK 8             // row = 8 chunks of 256 el (64 lanes x 4 el)
#define TOKENS_PER_OUT 8388608   // 1024*4*2048

// ---------- Threefry-2x32, 20 rounds, matches jax._src.prng ----------
__host__ __device__ __forceinline__ void tf2x32(uint32_t k0, uint32_t k1,
                                                uint32_t x0, uint32_t x1,
                                                uint32_t &o0, uint32_t &o1) {
  uint32_t ks2 = 0x1BD11BDAu ^ k0 ^ k1;
  x0 += k0; x1 += k1;
#define TFR(r) { x0 += x1; x1 = (x1 << (r)) | (x1 >> (32 - (r))); x1 ^= x0; }
  TFR(13) TFR(15) TFR(26) TFR(6)
  x0 += k1;  x1 += ks2 + 1u;
  TFR(17) TFR(29) TFR(16) TFR(24)
  x0 += ks2; x1 += k0 + 2u;
  TFR(13) TFR(15) TFR(26) TFR(6)
  x0 += k0;  x1 += k1 + 3u;
  TFR(17) TFR(29) TFR(16) TFR(24)
  x0 += k1;  x1 += ks2 + 4u;
  TFR(13) TFR(15) TFR(26) TFR(6)
  x0 += ks2; x1 += k0 + 5u;
#undef TFR
  o0 = x0; o1 = x1;
}

// 4 independent threefry streams; sched_barrier after each round keeps the
// 4-wide interleave intact through the machine scheduler.
__device__ __forceinline__ void tf4_bits(uint32_t k0, uint32_t k1,
                                         uint32_t cbase, uint32_t bits[4]) {
  const uint32_t ks2 = 0x1BD11BDAu ^ k0 ^ k1;
  uint32_t x0[4], x1[4];
#pragma unroll
  for (int i = 0; i < 4; ++i) { x0[i] = k0; x1[i] = (cbase + (uint32_t)i) + k1; }
#define TFR4(r)                                                         \
  _Pragma("unroll")                                                     \
  for (int i = 0; i < 4; ++i) {                                         \
    x0[i] += x1[i];                                                     \
    x1[i] = (x1[i] << (r)) | (x1[i] >> (32 - (r)));                     \
    x1[i] ^= x0[i];                                                     \
  }                                                                     \
  __builtin_amdgcn_sched_barrier(0);
#define INJ4(a, b)                                                      \
  _Pragma("unroll")                                                     \
  for (int i = 0; i < 4; ++i) { x0[i] += (a); x1[i] += (b); }
  TFR4(13) TFR4(15) TFR4(26) TFR4(6)
  INJ4(k1, ks2 + 1u)
  TFR4(17) TFR4(29) TFR4(16) TFR4(24)
  INJ4(ks2, k0 + 2u)
  TFR4(13) TFR4(15) TFR4(26) TFR4(6)
  INJ4(k0, k1 + 3u)
  TFR4(17) TFR4(29) TFR4(16) TFR4(24)
  INJ4(k1, ks2 + 4u)
  TFR4(13) TFR4(15) TFR4(26) TFR4(6)
  INJ4(ks2, k0 + 5u)
#undef TFR4
#undef INJ4
#pragma unroll
  for (int i = 0; i < 4; ++i) bits[i] = x0[i] ^ x1[i];
}

__device__ __forceinline__ float u01_from_bits(uint32_t bits) {
  return __uint_as_float((bits >> 9) | 0x3F800000u) - 1.0f;
}

#define SBAR() __builtin_amdgcn_sched_barrier(0)

// ---- DPP wave64 scan primitives (VALU ~2cy/step vs ds_bpermute ~30-40cy) ----
template<int CTRL, int RMASK>
__device__ __forceinline__ uint32_t dpp_mov0(uint32_t x) {
  // invalid/masked lanes yield 0 (old=0, bound_ctrl=false)
  return (uint32_t)__builtin_amdgcn_update_dpp(0, (int)x, CTRL, RMASK, 0xF, false);
}
// classic GCN wave64 inclusive prefix sum: row_shr 1/2/4/8, bcast15->rows 1,3,
// bcast31->rows 2,3
__device__ __forceinline__ uint32_t wave_incl_scan(uint32_t x) {
  x += dpp_mov0<0x111, 0xF>(x);   // row_shr:1
  x += dpp_mov0<0x112, 0xF>(x);   // row_shr:2
  x += dpp_mov0<0x114, 0xF>(x);   // row_shr:4
  x += dpp_mov0<0x118, 0xF>(x);   // row_shr:8
  x += dpp_mov0<0x142, 0xA>(x);   // row_bcast:15 into rows 1,3
  x += dpp_mov0<0x143, 0xC>(x);   // row_bcast:31 into rows 2,3
  return x;
}

// 8 correctly-rounded-quality f32 logs (positive normal f32 inputs), staged
// 8-wide with hard sched barriers so dependent f64 ops sit ~8 instrs apart.
// Bit-identical to the verified scalar math:
//   x = 2^e * m, m in [sqrt2/2, sqrt2), r = (m-1)*rcp(m+1) w/ 1 Newton,
//   log = e*ln2 + 2r*(1 + t/3 + .. + t^6/13).
__device__ __forceinline__ void log8_cr(const float x[8], float out[8]) {
#pragma clang fp contract(off)
  double m[8]; int e[8];
#pragma unroll
  for (int i = 0; i < 8; ++i) {
    uint32_t xb   = __float_as_uint(x[i]);
    uint32_t mant = xb & 0x7FFFFFu;
    int      ee   = (int)(xb >> 23) - 127;
    bool     big  = mant > 0x3504F3u;          // m > sqrt(2)
    e[i] = ee + (big ? 1 : 0);
    uint32_t hi = (big ? 0x3FE00000u : 0x3FF00000u) | (mant >> 3);
    uint32_t lo = mant << 29;
    m[i] = __longlong_as_double(((long long)hi << 32) | (long long)lo);
  }
  SBAR();
  double mp1[8];
#pragma unroll
  for (int i = 0; i < 8; ++i) mp1[i] = m[i] + 1.0;
  SBAR();
  double y[8];
#pragma unroll
  for (int i = 0; i < 8; ++i) y[i] = __builtin_amdgcn_rcp(mp1[i]);
  SBAR();
#pragma unroll
  for (int i = 0; i < 8; ++i) y[i] = fma(fma(-mp1[i], y[i], 1.0), y[i], y[i]);
  SBAR();
  double r[8];
#pragma unroll
  for (int i = 0; i < 8; ++i) r[i] = (m[i] - 1.0) * y[i];
  SBAR();
  double t[8];
#pragma unroll
  for (int i = 0; i < 8; ++i) t[i] = r[i] * r[i];
  SBAR();
  double p[8];
#pragma unroll
  for (int i = 0; i < 8; ++i) p[i] = fma(0.07692307692307693, t[i], 0.09090909090909091);
  SBAR();
#pragma unroll
  for (int i = 0; i < 8; ++i) p[i] = fma(p[i], t[i], 0.1111111111111111);
  SBAR();
#pragma unroll
  for (int i = 0; i < 8; ++i) p[i] = fma(p[i], t[i], 0.14285714285714285);
  SBAR();
#pragma unroll
  for (int i = 0; i < 8; ++i) p[i] = fma(p[i], t[i], 0.2);
  SBAR();
#pragma unroll
  for (int i = 0; i < 8; ++i) p[i] = fma(p[i], t[i], 0.3333333333333333);
  SBAR();
#pragma unroll
  for (int i = 0; i < 8; ++i) p[i] = fma(p[i], t[i], 1.0);
  SBAR();
#pragma unroll
  for (int i = 0; i < 8; ++i) r[i] = r[i] + r[i];       // 2r (exact)
  SBAR();
#pragma unroll
  for (int i = 0; i < 8; ++i) p[i] = r[i] * p[i];       // 2r*q
  SBAR();
#pragma unroll
  for (int i = 0; i < 8; ++i)
    out[i] = (float)fma((double)e[i], 0.6931471805599453, p[i]);
}

// scalar CR log (erfinv path only; same math, unstaged)
__device__ __forceinline__ float log_cr(float x) {
#pragma clang fp contract(off)
  uint32_t xb   = __float_as_uint(x);
  uint32_t mant = xb & 0x7FFFFFu;
  int      e    = (int)(xb >> 23) - 127;
  bool     big  = mant > 0x3504F3u;
  e += big ? 1 : 0;
  uint32_t hi = (big ? 0x3FE00000u : 0x3FF00000u) | (mant >> 3);
  double m = __longlong_as_double(((long long)hi << 32) | (long long)(mant << 29));
  double mp1 = m + 1.0;
  double y = __builtin_amdgcn_rcp(mp1);
  y = fma(fma(-mp1, y, 1.0), y, y);
  double r = (m - 1.0) * y;
  double t = r * r;
  double p = fma(0.07692307692307693, t, 0.09090909090909091);
  p = fma(p, t, 0.1111111111111111);
  p = fma(p, t, 0.14285714285714285);
  p = fma(p, t, 0.2);
  p = fma(p, t, 0.3333333333333333);
  p = fma(p, t, 1.0);
  return (float)fma((double)e, 0.6931471805599453, (r + r) * p);
}

// XLA ErfInv f32 expander (Giles poly), log1p per ElementalIrEmitter::EmitLog1p
__device__ float erfinv_xla(float x) {
#pragma clang fp contract(off)
  float x2  = x * x;
  float nx2 = -x2;
  float l1p;
  if (fabsf(nx2) < 1e-4f) {
    l1p = (-0.5f * nx2 + 1.0f) * nx2;
  } else {
    l1p = log_cr(1.0f + nx2);
  }
  float w = -l1p;
  float p;
  if (w < 5.0f) {
    float ww = w - 2.5f;
    p = 2.81022636e-08f;
    p = p * ww + 3.43273939e-07f;
    p = p * ww + -3.5233877e-06f;
    p = p * ww + -4.39150654e-06f;
    p = p * ww + 0.00021858087f;
    p = p * ww + -0.00125372503f;
    p = p * ww + -0.00417768164f;
    p = p * ww + 0.246640727f;
    p = p * ww + 1.50140941f;
  } else {
    float ww = sqrtf(w) - 3.0f;
    p = -0.000200214257f;
    p = p * ww + 0.000100950558f;
    p = p * ww + 0.00134934322f;
    p = p * ww + -0.00367342844f;
    p = p * ww + 0.00573950773f;
    p = p * ww + -0.0076224613f;
    p = p * ww + 0.00943887047f;
    p = p * ww + 1.00167406f;
    p = p * ww + 2.83297682f;
  }
  return p * x;
}

// R10: wave-per-row + IN-REGISTER BISECTION SELECT -- zero LDS, zero atomics,
// zero barriers. R8/R9 localized the residual to the DS pipe: the histogram
// select pushes ~1.3k DS instrs/CU (zero-writes + scatter/same-address
// atomics + reads) with dependent lgkmcnt waits from lockstepped waves into
// ONE shared DS pipe -- queueing, not VALU, was the stall. Replacement:
// per-lane 32x32 bit-transpose (Hacker's Delight, ~480 VALU ops) turns the
// 32 keys into 32 per-bit masks M[b]; a 32-step binary search with
// DPP-reduced popcounts finds T exactly: active(=T set), above(>T set),
// r = remaining -- identical semantics to the verified radix select. The
// whole select is ~900 pure-VALU instrs with NO memory round-trips, so
// 4 waves/SIMD (grid-capped) saturate issue. LDS usage: ZERO.
// Mapping: after transpose, M[b] = mloc[31-b]; value k lives at bit 31-k.
__global__ __launch_bounds__(NTHREADS, 4)
void gumbel_topk_mask(const float* __restrict__ wfull,   // (B,C,2S) f32
                      const int*   __restrict__ attn,    // (B,C,S) i32
                      const int*   __restrict__ ids,     // (B,C,S) i32
                      int* __restrict__ out,             // 3x(B,C,S) i32 concat
                      uint32_t kg0, uint32_t kg1, uint32_t kn0, uint32_t kn1) {
#pragma clang fp contract(off)
  const int t    = threadIdx.x;
  const int lane = t & 63;
  const int wid  = t >> 6;
  const int row  = blockIdx.x * ROWS_PER_BLOCK + wid;

  const size_t rbase = (size_t)row * SLEN;
  const size_t wbase = (size_t)row * (2 * SLEN);

  const int4*   av4 = (const int4*)(attn + rbase);
  const float4* wv4 = (const float4*)(wfull + wbase);
  const int4*   iv4 = (const int4*)(ids + rbase);

  // ---- attn + w loads issued up front (coalesced: lane stride 16B);
  // w consumed ~5k cycles later under the threefry/f64 pipeline ----
  int psum = 0;
#pragma unroll
  for (int j = 0; j < NCHUNK; ++j) {
    int4 a = av4[64 * j + lane];
    psum += a.x + a.y + a.z + a.w;
  }
  float4 wC[NCHUNK];
#pragma unroll
  for (int j = 0; j < NCHUNK; ++j) wC[j] = wv4[64 * j + lane];

  // ---- frac (load-independent long f64 chain; hides load latency) ----
  uint32_t no0, no1;
  tf2x32(kn0, kn1, 0u, (uint32_t)row, no0, no1);
  float f0  = u01_from_bits(no0 ^ no1);
  float lo  = __uint_as_float(0xBF7FFFFFu);        // nextafter(-1,0)
  float u2  = fmaxf(lo, f0 * 2.0f + lo);           // (1-lo) rounds to 2.0f
  float z   = erfinv_xla(u2);
  float nrm = 1.4142135623730951f * z;
  float frac = 0.15f + 0.0375f * nrm;

  // ---- row attention sum: DPP scan + readlane(63) -- no LDS ----
  uint32_t ps = wave_incl_scan((uint32_t)psum);
  int asum = (int)__builtin_amdgcn_readlane((int)ps, 63);
  int kk = (int)floorf((float)asum * frac);

  // ---- key pipeline: 4 chunk-pairs x 8 elements (forced-ILP) ----
  // mloc[4*j + e] <=> chunk j (indices 256j + 4*lane + e)
  uint32_t mloc[EPT];
#pragma unroll
  for (int c = 0; c < 4; ++c) {
    float4 wa = wC[2 * c], wb = wC[2 * c + 1];
    uint32_t bits[8];
    tf4_bits(kg0, kg1, (uint32_t)(rbase + 256 * (2 * c)     + 4 * lane), bits + 0);
    tf4_bits(kg0, kg1, (uint32_t)(rbase + 256 * (2 * c + 1) + 4 * lane), bits + 4);
    SBAR();
    float wl8[8] = {wa.x, wa.y, wa.z, wa.w, wb.x, wb.y, wb.z, wb.w};
    float uu[8];
#pragma unroll
    for (int e = 0; e < 8; ++e) {
      float f = u01_from_bits(bits[e]);
      uu[e] = fmaxf(1.17549435e-38f, f * 1.0f + 1.17549435e-38f);
    }
    SBAR();
    float l1[8];
    log8_cr(uu, l1);                       // log u
    float wm[8];
#pragma unroll
    for (int e = 0; e < 8; ++e) wm[e] = fmaxf(wl8[e], 1e-30f);
    float lw[8];
    log8_cr(wm, lw);                       // log w
    float nl1[8];
#pragma unroll
    for (int e = 0; e < 8; ++e) nl1[e] = -l1[e];
    float l2[8];
    log8_cr(nl1, l2);                      // log(-log u); gumbel = -l2
    SBAR();
#pragma unroll
    for (int e = 0; e < 8; ++e) {
      float key = (wl8[e] > 0.0f) ? (lw[e] + (-l2[e])) : -__builtin_inff();
      uint32_t kb = __float_as_uint(key);
      mloc[8 * c + e] = (kb & 0x80000000u) ? ~kb : (kb | 0x80000000u);  // monotone
    }
  }

  // ids loads: issue now, consumed in epilogue (hidden under the select)
  int4 idsv[NCHUNK];
#pragma unroll
  for (int j = 0; j < NCHUNK; ++j) idsv[j] = iv4[64 * j + lane];

  // ---- in-place 32x32 bit transpose (Hacker's Delight), fully unrolled ----
  // After: bit p of mloc[i] = bit (31-i) of original value (31-p).
  // => per-bit mask M[b] = mloc[31-b], value k <-> bit position 31-k.
  {
    const uint32_t MSK[5] = {0x0000FFFFu, 0x00FF00FFu, 0x0F0F0F0Fu,
                             0x33333333u, 0x55555555u};
#pragma unroll
    for (int jj = 0; jj < 5; ++jj) {
      const int j = 16 >> jj;
      const uint32_t m = MSK[jj];
#pragma unroll
      for (int k = 0; k < 32; ++k) {
        if ((k & j) == 0) {                     // compile-time predicate
          uint32_t tt = (mloc[k] ^ (mloc[k + j] >> j)) & m;
          mloc[k]     ^= tt;
          mloc[k + j] ^= (tt << j);
        }
      }
    }
  }

  // ---- 32-step in-register bisection for the k-th largest key ----
  uint32_t above, active, r;
  if (kk <= 0)          { above = 0u;          active = 0u; r = 0u; }  // none
  else if (kk >= SLEN)  { above = 0xFFFFFFFFu; active = 0u; r = 0u; }  // all
  else {
    above = 0u; active = 0xFFFFFFFFu;
    uint32_t need = (uint32_t)kk;
#pragma unroll
    for (int b = 31; b >= 0; --b) {
      uint32_t M    = mloc[31 - b];        // mask: values with bit b set
      uint32_t cand = active & M;
      uint32_t c    = (uint32_t)__popc(cand);
      uint32_t P    = wave_incl_scan(c);
      uint32_t tot  = (uint32_t)__builtin_amdgcn_readlane((int)P, 63);
      bool hi = (need <= tot);             // uniform across the wave
      above  = hi ? above : (above | cand);
      need   = hi ? need  : (need - tot);
      active = hi ? cand  : (active & ~M);
    }
    r = need;                              // take first r (by index) among ==T
  }

  // ---- stable tie-break in INDEX order: eq bits straight from `active` ----
  // chunk j = values 4j..4j+3 = bits (28-4j)..(31-4j)
  uint32_t cnt[NCHUNK];
#pragma unroll
  for (int j = 0; j < NCHUNK; ++j)
    cnt[j] = (uint32_t)__popc(active & (0xFu << (28 - 4 * j)));
  uint32_t incl[4];
#pragma unroll
  for (int q = 0; q < 4; ++q)
    incl[q] = wave_incl_scan(cnt[2 * q] | (cnt[2 * q + 1] << 16));
  uint32_t Spre[NCHUNK], tot[NCHUNK];
#pragma unroll
  for (int q = 0; q < 4; ++q) {
    uint32_t t63 = (uint32_t)__builtin_amdgcn_readlane((int)incl[q], 63);
    tot[2 * q]      = t63 & 0xFFFFu;
    tot[2 * q + 1]  = t63 >> 16;
    Spre[2 * q]     = (incl[q] & 0xFFFFu) - cnt[2 * q];
    Spre[2 * q + 1] = (incl[q] >> 16)     - cnt[2 * q + 1];
  }

  // ---- epilogue: masked writes (coalesced, fire-and-forget) ----
  int4* po = (int4*)(out + rbase);
  int4* pm = (int4*)(out + TOKENS_PER_OUT + rbase);
  int4* pl = (int4*)(out + 2 * TOKENS_PER_OUT + rbase);
  uint32_t C = 0;   // eq-count in chunks before j (uniform across lanes)
#pragma unroll
  for (int j = 0; j < NCHUNK; ++j) {
    uint32_t excl = C + Spre[j];
    int4 iv = idsv[j];
    int idv[4] = {iv.x, iv.y, iv.z, iv.w};
    int oid[4], omk[4], olb[4];
#pragma unroll
    for (int e = 0; e < 4; ++e) {
      const int bit = 31 - (4 * j + e);
      bool eq  = (active >> bit) & 1u;
      bool abv = (above  >> bit) & 1u;
      bool msk = abv || (eq && (excl < r));
      excl += eq ? 1u : 0u;
      oid[e] = msk ? 103 : idv[e];      // MASK_ID
      omk[e] = msk ? 1 : 0;
      olb[e] = msk ? -1 : 0;
    }
    po[64 * j + lane] = make_int4(oid[0], oid[1], oid[2], oid[3]);
    pm[64 * j + lane] = make_int4(omk[0], omk[1], omk[2], omk[3]);
    pl[64 * j + lane] = make_int4(olb[0], olb[1], olb[2], olb[3]);
    C += tot[j];
  }
}

extern "C" void kernel_launch(void* const* d_in, const int* in_sizes, int n_in,
                              void* d_out, int out_size, void* d_ws, size_t ws_size,
                              hipStream_t stream) {
  (void)n_in; (void)d_ws; (void)ws_size; (void)out_size;
  const float* wfull = (const float*)d_in[0];   // my_attention_mask (B,C,2S)
  const int*   attn  = (const int*)d_in[1];     // attention_mask    (B,C,S)
  const int*   ids   = (const int*)d_in[2];     // input_ids         (B,C,S)
  int* out = (int*)d_out;

  // jax.random.key(42) -> (0,42); partitionable split: kg=enc(key,(0,0)), kn=enc(key,(0,1))
  uint32_t kg0, kg1, kn0, kn1, o0, o1;
  tf2x32(0u, 42u, 0u, 0u, o0, o1); kg0 = o0; kg1 = o1;
  tf2x32(0u, 42u, 0u, 1u, o0, o1); kn0 = o0; kn1 = o1;

  int rows = in_sizes[1] / SLEN;                // 4096
  hipLaunchKernelGGL(gumbel_topk_mask, dim3(rows / ROWS_PER_BLOCK), dim3(NTHREADS),
                     0, stream, wfull, attn, ids, out, kg0, kg1, kn0, kn1);
}